// Round 18
// baseline (163.919 us; speedup 1.0000x reference)
//
#include <hip/hip_runtime.h>
#include <hip/hip_bf16.h>
#include <stdint.h>

#define D_EMB 128
#define D_NLP 768
#define BM 64
#define BK 64
#define NKC (D_NLP / BK)   // 12 k-chunks
#define TUNITS 6144        // 16B-units per tile: 12 chunks x 512

typedef __attribute__((ext_vector_type(8))) short bf16x8;
typedef __attribute__((ext_vector_type(4))) float f32x4;
typedef __attribute__((ext_vector_type(8))) unsigned short u16x8;

__device__ __forceinline__ unsigned short f2bf(float f) {
  unsigned u = __builtin_bit_cast(unsigned, f);
  u += 0x7fffu + ((u >> 16) & 1u);   // RTNE (NaN-free inputs)
  return (unsigned short)(u >> 16);
}

__device__ __forceinline__ u16x8 pack8u(const float4& a, const float4& b) {
  u16x8 v;
  v[0] = f2bf(a.x); v[1] = f2bf(a.y); v[2] = f2bf(a.z); v[3] = f2bf(a.w);
  v[4] = f2bf(b.x); v[5] = f2bf(b.y); v[6] = f2bf(b.z); v[7] = f2bf(b.w);
  return v;
}
__device__ __forceinline__ bf16x8 pack8(const float4& a, const float4& b) {
  return __builtin_bit_cast(bf16x8, pack8u(a, b));
}

// ---- kernel W: w0 -> bf16, pre-swizzled per 64-k chunk (B path). init mn.
__global__ void kw(const float* __restrict__ w0, unsigned short* __restrict__ w0s,
                   int* __restrict__ mn) {
  if (blockIdx.x == 0 && threadIdx.x == 0) mn[0] = 0x7fffffff;
  int t = blockIdx.x * 256 + threadIdx.x;       // 12288 units
  if (t >= (D_EMB * D_NLP) / 8) return;
  int u = t & 7, row = (t >> 3) & 127, kc = t >> 10;
  const float4* src = (const float4*)(w0 + (size_t)row * D_NLP + kc * 64 + ((u ^ (row & 7)) * 8));
  *(u16x8*)(w0s + (size_t)t * 8) = pack8u(src[0], src[1]);
}

// ---- kernel M: mn = min_e max(ei[0][e], ei[1][e])
__global__ void km(const int* __restrict__ ei, int E, int* __restrict__ mn) {
  int t = blockIdx.x * blockDim.x + threadIdx.x;
  int stride = gridDim.x * blockDim.x;
  int m = 0x7fffffff;
  for (int e = t; e < E; e += stride) {
    int a = ei[e], b = ei[E + e];
    int q = a > b ? a : b;
    m = q < m ? q : m;
  }
  #pragma unroll
  for (int off = 32; off; off >>= 1) {
    int o = __shfl_xor(m, off);
    m = o < m ? o : m;
  }
  if ((threadIdx.x & 63) == 0) atomicMin(mn, m);
}

// ---- kernel Z: sequential-read repack. z0 f32 row-major -> zt bf16 tiled
// [tile][chunk][row][k-unit] with the LDS swizzle pre-baked (unit j of row r
// lands at r*8 + (j ^ (r&7))). Reads are row-major contiguous (page-perfect);
// writes are dense 128B segments.
__global__ void kz(const float* __restrict__ z0, unsigned short* __restrict__ zt,
                   int N, int units_total) {
  int g = blockIdx.x * 256 + threadIdx.x;
  if (g >= units_total) return;
  unsigned rg = (unsigned)g / 96u;         // global padded row
  int u = g - (int)rg * 96;                // unit within row 0..95
  int srow = min((int)rg, N - 1);
  const float4* s = (const float4*)(z0 + (size_t)srow * D_NLP + u * 8);
  float4 a = s[0], b = s[1];
  int T = rg >> 6, r = rg & 63, c = u >> 3, j = u & 7;
  size_t dst = (size_t)T * TUNITS + c * 512 + r * 8 + (j ^ (r & 7));
  *(u16x8*)(zt + dst * 8) = pack8u(a, b);
}

// ---- kernel C2 (fast path): A from zt (bf16, tiled, L3-hot after kz).
// Per chunk the A-stage is 8KB CONTIGUOUS (2 instrs/wave of 1KB, PER-LANE
// source = base + lane*16B -- the R17 bug was a wave-uniform source).
// A ring-3 (3x8KB) + B ring-2 (2x16KB) = 56KB static -> 2 blocks/CU.
// No pack8 in the loop. Counted vmcnt(2); fused sv + z-dot epilogues.
__global__ __launch_bounds__(256) void kc2(
    const unsigned short* __restrict__ zt, const float* __restrict__ z,
    const unsigned short* __restrict__ w0s, const float* __restrict__ w1,
    const float* __restrict__ prelu_a, float* __restrict__ sv,
    float* __restrict__ ta, float* __restrict__ tb, int N) {
  __shared__ unsigned short Al[3][512 * 8];   // 3 x 8KB
  __shared__ unsigned short Bl[2][8192];      // 2 x 16KB

  const int tid = threadIdx.x;
  const int lane = tid & 63;
  const int wave = tid >> 6;
  const int kg = lane >> 4;
  const int col = lane & 15;
  const int r0 = blockIdx.x * BM;
  const int myrow = r0 + wave * 16 + col;
  const int arow_g = min(myrow, N - 1);
  const size_t abase = (size_t)blockIdx.x * TUNITS;

  auto stageA = [&](int t, int buf) {
    // PER-LANE source: lane reads unit (wave*128 + i*64 + lane) of chunk t
    const unsigned short* g =
        zt + (abase + (size_t)t * 512 + (size_t)(wave * 128 + lane)) * 8;
    #pragma unroll
    for (int i = 0; i < 2; ++i) {
      __builtin_amdgcn_global_load_lds(
          (const __attribute__((address_space(1))) void*)(g + i * 64 * 8),
          (__attribute__((address_space(3))) void*)&Al[buf][(wave * 128 + i * 64) * 8],
          16, 0, 0);
    }
  };
  auto stageB = [&](int t, int buf) {
    const unsigned short* g = w0s + (size_t)t * (D_EMB * BK) + (size_t)tid * 8;
    #pragma unroll
    for (int p = 0; p < 4; ++p) {
      __builtin_amdgcn_global_load_lds(
          (const __attribute__((address_space(1))) void*)(g + p * 256 * 8),
          (__attribute__((address_space(3))) void*)&Bl[buf][(wave * 64 + p * 256) * 8],
          16, 0, 0);
    }
  };

  f32x4 acc[8];
  #pragma unroll
  for (int c = 0; c < 8; ++c) acc[c] = (f32x4){0.f, 0.f, 0.f, 0.f};

  stageB(0, 0);
  stageA(0, 0);
  stageA(1, 1);

  const int arw = (wave * 16 + col) * 8;   // A unit-row base
  const int asw = col & 7;

  #pragma unroll
  for (int t = 0; t < NKC; ++t) {
    if (t < NKC - 1) asm volatile("s_waitcnt vmcnt(2)" ::: "memory");
    else             asm volatile("s_waitcnt vmcnt(0)" ::: "memory");
    __builtin_amdgcn_s_barrier();
    if (t + 1 < NKC) stageB(t + 1, (t + 1) & 1);
    if (t + 2 < NKC) stageA(t + 2, (t + 2) % 3);
    __builtin_amdgcn_sched_barrier(0);

    const unsigned short* Ab = Al[t % 3];
    const unsigned short* Bbuf = Bl[t & 1];
    #pragma unroll
    for (int ks = 0; ks < 2; ++ks) {
      bf16x8 af = *(const bf16x8*)&Ab[(arw + ((ks * 4 + kg) ^ asw)) * 8];
      #pragma unroll
      for (int c = 0; c < 8; ++c) {
        int brow = c * 16 + col;
        bf16x8 bfr = *(const bf16x8*)&Bl[t & 1][(brow * 8 + ((ks * 4 + kg) ^ (brow & 7))) * 8];
        acc[c] = __builtin_amdgcn_mfma_f32_16x16x32_bf16(af, bfr, acc[c], 0, 0, 0);
      }
      (void)Bbuf;
    }
  }

  // epilogue 1: prelu + * w1c, 16-lane-group reduce
  float ap = prelu_a[0];
  float ssum[4] = {0.f, 0.f, 0.f, 0.f};
  #pragma unroll
  for (int c = 0; c < 8; ++c) {
    float wc = w1[2 * D_EMB + c * 16 + col];
    #pragma unroll
    for (int i = 0; i < 4; ++i) {
      float h = acc[c][i];
      float x = h >= 0.f ? h : ap * h;
      ssum[i] += x * wc;
    }
  }
  #pragma unroll
  for (int off = 1; off < 16; off <<= 1) {
    #pragma unroll
    for (int i = 0; i < 4; ++i) ssum[i] += __shfl_xor(ssum[i], off);
  }
  if (col == 0) {
    int rbase = r0 + wave * 16 + kg * 4;
    #pragma unroll
    for (int i = 0; i < 4; ++i) {
      int r = rbase + i;
      if (r < N) sv[r] = ssum[i];
    }
  }

  // epilogue 2 (fused kt)
  {
    const float* zp = z + (size_t)arow_g * D_EMB + kg * 32;
    const float4* wa4 = (const float4*)(w1 + kg * 32);
    const float4* wb4 = (const float4*)(w1 + D_EMB + kg * 32);
    float pa = 0.f, pb = 0.f;
    #pragma unroll
    for (int i = 0; i < 8; ++i) {
      float4 zv = ((const float4*)zp)[i];
      float4 wa = wa4[i];
      float4 wb = wb4[i];
      pa += zv.x * wa.x + zv.y * wa.y + zv.z * wa.z + zv.w * wa.w;
      pb += zv.x * wb.x + zv.y * wb.y + zv.z * wb.z + zv.w * wb.w;
    }
    pa += __shfl_xor(pa, 16); pa += __shfl_xor(pa, 32);
    pb += __shfl_xor(pb, 16); pb += __shfl_xor(pb, 32);
    if (kg == 0 && myrow < N) { ta[myrow] = pa; tb[myrow] = pb; }
  }
}

// ---- kernel C1 (fallback, R11 verbatim): used when ws can't hold zt.
__global__ __launch_bounds__(256) void kc1(
    const float* __restrict__ z0, const float* __restrict__ z,
    const unsigned short* __restrict__ w0s, const float* __restrict__ w1,
    const float* __restrict__ prelu_a, float* __restrict__ sv,
    float* __restrict__ ta, float* __restrict__ tb, int N) {
  extern __shared__ char smem[];
  float* Al = (float*)smem;
  unsigned short* Bl = (unsigned short*)(smem + 49152);

  const int tid = threadIdx.x;
  const int lane = tid & 63;
  const int wave = tid >> 6;
  const int kg = lane >> 4;
  const int col = lane & 15;
  const int s16 = lane & 15;
  const int hl = lane >> 4;
  const int r0 = blockIdx.x * BM;
  const int myrow = r0 + wave * 16 + col;
  const int arow_g = min(myrow, N - 1);

  const float* aSrc[4];
  #pragma unroll
  for (int p = 0; p < 4; ++p) {
    int rl = p * 4 + hl;
    int rg = min(r0 + wave * 16 + rl, N - 1);
    int cu = s16 ^ (rl & 7);
    aSrc[p] = z0 + (size_t)rg * D_NLP + cu * 4;
  }

  auto stageA = [&](int t, int buf) {
    #pragma unroll
    for (int p = 0; p < 4; ++p) {
      __builtin_amdgcn_global_load_lds(
          (const __attribute__((address_space(1))) void*)(aSrc[p] + t * BK),
          (__attribute__((address_space(3))) void*)&Al[buf * 4096 + (wave * 16 + p * 4) * 64],
          16, 0, 0);
    }
  };
  auto stageB = [&](int t, int buf) {
    const unsigned short* g = w0s + (size_t)t * (D_EMB * BK) + (size_t)tid * 8;
    #pragma unroll
    for (int p = 0; p < 4; ++p) {
      __builtin_amdgcn_global_load_lds(
          (const __attribute__((address_space(1))) void*)(g + p * 256 * 8),
          (__attribute__((address_space(3))) void*)&Bl[buf * 8192 + (wave * 64 + p * 256) * 8],
          16, 0, 0);
    }
  };

  f32x4 acc[8];
  #pragma unroll
  for (int c = 0; c < 8; ++c) acc[c] = (f32x4){0.f, 0.f, 0.f, 0.f};

  stageB(0, 0);
  stageA(0, 0);
  stageA(1, 1);

  const int arow_l = (wave * 16 + col) * 64;
  const int asw = col & 7;

  #pragma unroll
  for (int t = 0; t < NKC; ++t) {
    if (t < NKC - 1) asm volatile("s_waitcnt vmcnt(4)" ::: "memory");
    else             asm volatile("s_waitcnt vmcnt(0)" ::: "memory");
    __builtin_amdgcn_s_barrier();
    if (t + 1 < NKC) stageB(t + 1, (t + 1) & 1);
    if (t + 2 < NKC) stageA(t + 2, (t + 2) % 3);
    __builtin_amdgcn_sched_barrier(0);

    const float* Ab = Al + (t % 3) * 4096;
    const unsigned short* Bbuf = Bl + (t & 1) * 8192;
    #pragma unroll
    for (int ks = 0; ks < 2; ++ks) {
      int u0 = ks * 8 + kg * 2;
      float4 lo = *(const float4*)&Ab[arow_l + ((u0)     ^ asw) * 4];
      float4 hi = *(const float4*)&Ab[arow_l + ((u0 + 1) ^ asw) * 4];
      bf16x8 af = pack8(lo, hi);
      #pragma unroll
      for (int c = 0; c < 8; ++c) {
        int brow = c * 16 + col;
        bf16x8 bfr = *(const bf16x8*)&Bbuf[(brow * 8 + ((ks * 4 + kg) ^ (brow & 7))) * 8];
        acc[c] = __builtin_amdgcn_mfma_f32_16x16x32_bf16(af, bfr, acc[c], 0, 0, 0);
      }
    }
  }

  float ap = prelu_a[0];
  float ssum[4] = {0.f, 0.f, 0.f, 0.f};
  #pragma unroll
  for (int c = 0; c < 8; ++c) {
    float wc = w1[2 * D_EMB + c * 16 + col];
    #pragma unroll
    for (int i = 0; i < 4; ++i) {
      float h = acc[c][i];
      float x = h >= 0.f ? h : ap * h;
      ssum[i] += x * wc;
    }
  }
  #pragma unroll
  for (int off = 1; off < 16; off <<= 1) {
    #pragma unroll
    for (int i = 0; i < 4; ++i) ssum[i] += __shfl_xor(ssum[i], off);
  }
  if (col == 0) {
    int rbase = r0 + wave * 16 + kg * 4;
    #pragma unroll
    for (int i = 0; i < 4; ++i) {
      int r = rbase + i;
      if (r < N) sv[r] = ssum[i];
    }
  }
  {
    const float* zp = z + (size_t)arow_g * D_EMB + kg * 32;
    const float4* wa4 = (const float4*)(w1 + kg * 32);
    const float4* wb4 = (const float4*)(w1 + D_EMB + kg * 32);
    float pa = 0.f, pb = 0.f;
    #pragma unroll
    for (int i = 0; i < 8; ++i) {
      float4 zv = ((const float4*)zp)[i];
      float4 wa = wa4[i];
      float4 wb = wb4[i];
      pa += zv.x * wa.x + zv.y * wa.y + zv.z * wa.z + zv.w * wa.w;
      pb += zv.x * wb.x + zv.y * wb.y + zv.z * wb.z + zv.w * wb.w;
    }
    pa += __shfl_xor(pa, 16); pa += __shfl_xor(pa, 32);
    pb += __shfl_xor(pb, 16); pb += __shfl_xor(pb, 32);
    if (kg == 0 && myrow < N) { ta[myrow] = pa; tb[myrow] = pb; }
  }
}

// ---- kernel D: per-edge gather + add
__global__ void kd(const int* __restrict__ ei, const int* __restrict__ mn,
                   const float* __restrict__ ta, const float* __restrict__ tb,
                   const float* __restrict__ sv, const float* __restrict__ b1,
                   float* __restrict__ out, int E) {
  int e = blockIdx.x * blockDim.x + threadIdx.x;
  if (e >= E) return;
  int i0 = ei[e], i1 = ei[E + e];
  int q = (i0 > i1 ? i0 : i1) - mn[0];
  out[e] = ta[i0] + tb[i1] + sv[q] + b1[0];
}

extern "C" void kernel_launch(void* const* d_in, const int* in_sizes, int n_in,
                              void* d_out, int out_size, void* d_ws, size_t ws_size,
                              hipStream_t stream) {
  const float* z  = (const float*)d_in[0];
  const float* z0 = (const float*)d_in[1];
  const int*   ei = (const int*)d_in[2];
  const float* w0 = (const float*)d_in[3];
  const float* pa = (const float*)d_in[4];
  const float* w1 = (const float*)d_in[5];
  const float* b1 = (const float*)d_in[6];
  float* out = (float*)d_out;
  const int N = in_sizes[0] / D_EMB;
  const int E = in_sizes[2] / 2;
  const int NT = (N + BM - 1) / BM;

  // ws: [0,4) mn | [256,+192KB) w0s | ta[N], tb[N], sv[N] | zt @ 4MB (~154MB)
  char* ws = (char*)d_ws;
  int* mn = (int*)ws;
  unsigned short* w0s = (unsigned short*)(ws + 256);
  float* ta = (float*)(ws + 256 + 196608);
  float* tb = ta + N;
  float* sv = tb + N;
  const size_t zt_off = (size_t)4 << 20;
  unsigned short* zt = (unsigned short*)(ws + zt_off);
  const size_t need = zt_off + (size_t)NT * TUNITS * 16;
  const bool big = ws_size >= need;

  kw<<<(D_EMB * D_NLP / 8 + 255) / 256, 256, 0, stream>>>(w0, w0s, mn);
  km<<<256, 256, 0, stream>>>(ei, E, mn);
  if (big) {
    const int units = NT * BM * (D_NLP / 8);
    kz<<<(units + 255) / 256, 256, 0, stream>>>(z0, zt, N, units);
    kc2<<<NT, 256, 0, stream>>>(zt, z, w0s, w1, pa, sv, ta, tb, N);
  } else {
    hipFuncSetAttribute((const void*)kc1,
                        hipFuncAttributeMaxDynamicSharedMemorySize, 81920);
    kc1<<<NT, 256, 81920, stream>>>(z0, z, w0s, w1, pa, sv, ta, tb, N);
  }
  kd<<<(E + 255) / 256, 256, 0, stream>>>(ei, mn, ta, tb, sv, b1, out, E);
}